// Round 1
// baseline (179.840 us; speedup 1.0000x reference)
//
#include <hip/hip_runtime.h>

// SlotEquivariantHead: 16-step digit scan, each step a 3-layer MLP (162->256->256->96)
// over B=16384 rows; 32 carry dims fed back between steps.
// Strategy: batch-parallel blocks (64 rows each), bf16 MFMA (16x16x32) with f32 accum,
// weights pre-packed into MFMA B-fragment layout in d_ws, activations in LDS.

#define XS 200   // X LDS row stride (elems): 192 K-pad + 8 pad (400B, 16B-aligned, odd-ish banks)
#define HS 264   // H LDS row stride (elems): 256 + 8 pad (528B, 16B-aligned)

typedef __attribute__((ext_vector_type(8))) short bf16x8;
typedef __attribute__((ext_vector_type(4))) float f32x4;

__device__ inline unsigned short f32_to_bf16(float f) {
  unsigned int u = __builtin_bit_cast(unsigned int, f);
  u += 0x7FFFu + ((u >> 16) & 1u);   // round-to-nearest-even
  return (unsigned short)(u >> 16);
}

// Pack W1 (162x256, K-pad to 192), W2 (256x256), W3 (256x96) into bf16 MFMA
// B-fragment layout: frag(kk,nt): lane l, elem j  <-  W[kk*32 + (l>>4)*8 + j][nt*16 + (l&15)]
// Layout in d_ws (elems): W1p [0, 49152), W2p [49152, 114688), W3p [114688, 139264)
__global__ void pack_weights_kernel(const float* __restrict__ W1,
                                    const float* __restrict__ W2,
                                    const float* __restrict__ W3,
                                    unsigned short* __restrict__ wp) {
  int idx = blockIdx.x * 256 + threadIdx.x;
  if (idx >= 139264) return;
  const float* W; int K, N, NT, e;
  if (idx < 49152)       { W = W1; K = 162; N = 256; NT = 16; e = idx; }
  else if (idx < 114688) { W = W2; K = 256; N = 256; NT = 16; e = idx - 49152; }
  else                   { W = W3; K = 256; N = 96;  NT = 6;  e = idx - 114688; }
  int j = e & 7, lane = (e >> 3) & 63, frag = e >> 9;
  int nt = frag % NT, kk = frag / NT;
  int k = kk * 32 + ((lane >> 4) << 3) + j;
  int n = nt * 16 + (lane & 15);
  float v = (k < K) ? W[k * N + n] : 0.0f;
  wp[idx] = f32_to_bf16(v);
}

__global__ __launch_bounds__(512) void scan_kernel(
    const float* __restrict__ Ain, const float* __restrict__ Bin,
    const float* __restrict__ Op,
    const float* __restrict__ b1, const float* __restrict__ b2,
    const float* __restrict__ b3,
    const unsigned short* __restrict__ wp,
    float* __restrict__ out) {
  extern __shared__ unsigned short lds[];
  unsigned short* X  = lds;               // [64][XS]  x = [a|b|op|carry|zpad]
  unsigned short* H1 = lds + 64 * XS;     // [64][HS]
  unsigned short* H2 = H1 + 64 * HS;      // [64][HS]

  const unsigned short* W1p = wp;
  const unsigned short* W2p = wp + 49152;
  const unsigned short* W3p = wp + 114688;

  const int tid  = threadIdx.x;
  const int wave = tid >> 6, lane = tid & 63;
  const int lrow = lane & 15;             // A row / B col / C col within tile
  const int lkb  = (lane >> 4) << 3;      // per-lane K base (contiguous 8)
  const int crow = (lane >> 4) << 2;      // C row base within tile
  const int row0 = blockIdx.x * 64;

  const f32x4 zero4 = {0.f, 0.f, 0.f, 0.f};

  // init persistent X columns: op (128,129), carry=0 (130..161), K-pad=0 (162..191)
  for (int i = tid; i < 64 * 64; i += 512) {
    int r = i >> 6, c = 128 + (i & 63);
    unsigned short v = 0;
    if (c < 130) v = f32_to_bf16(Op[(row0 + r) * 2 + (c - 128)]);
    X[r * XS + c] = v;
  }

  for (int p = 0; p < 16; ++p) {
    // stage this position's a,b digit slices (cols 0..127)
    for (int i = tid; i < 2048; i += 512) {
      int tsr = i >> 10;                 // 0 = a, 1 = b
      int r = (i >> 4) & 63;
      int c4 = (i & 15) << 2;
      const float* src = tsr ? Bin : Ain;
      float4 v = *(const float4*)&src[(size_t)(row0 + r) * 1024 + p * 64 + c4];
      int base = r * XS + tsr * 64 + c4;
      X[base + 0] = f32_to_bf16(v.x);
      X[base + 1] = f32_to_bf16(v.y);
      X[base + 2] = f32_to_bf16(v.z);
      X[base + 3] = f32_to_bf16(v.w);
    }
    __syncthreads();

    // ---- layer 1: X[64x192] @ W1p -> relu -> H1[64x256]
    {
      f32x4 acc[4][2];
      #pragma unroll
      for (int m = 0; m < 4; ++m) { acc[m][0] = zero4; acc[m][1] = zero4; }
      const int nt0 = wave * 2;
      #pragma unroll
      for (int kk = 0; kk < 6; ++kk) {
        bf16x8 a[4];
        #pragma unroll
        for (int m = 0; m < 4; ++m)
          a[m] = *(const bf16x8*)&X[(m * 16 + lrow) * XS + kk * 32 + lkb];
        #pragma unroll
        for (int nn = 0; nn < 2; ++nn) {
          bf16x8 b = *(const bf16x8*)&W1p[((kk * 16 + nt0 + nn) * 64 + lane) * 8];
          #pragma unroll
          for (int m = 0; m < 4; ++m)
            acc[m][nn] = __builtin_amdgcn_mfma_f32_16x16x32_bf16(a[m], b, acc[m][nn], 0, 0, 0);
        }
      }
      #pragma unroll
      for (int nn = 0; nn < 2; ++nn) {
        float bias = b1[(nt0 + nn) * 16 + lrow];
        #pragma unroll
        for (int m = 0; m < 4; ++m) {
          #pragma unroll
          for (int i = 0; i < 4; ++i) {
            float v = acc[m][nn][i] + bias;
            v = v > 0.f ? v : 0.f;
            H1[(m * 16 + crow + i) * HS + (nt0 + nn) * 16 + lrow] = f32_to_bf16(v);
          }
        }
      }
    }
    __syncthreads();

    // ---- layer 2: H1[64x256] @ W2p -> relu -> H2[64x256]
    {
      f32x4 acc[4][2];
      #pragma unroll
      for (int m = 0; m < 4; ++m) { acc[m][0] = zero4; acc[m][1] = zero4; }
      const int nt0 = wave * 2;
      #pragma unroll
      for (int kk = 0; kk < 8; ++kk) {
        bf16x8 a[4];
        #pragma unroll
        for (int m = 0; m < 4; ++m)
          a[m] = *(const bf16x8*)&H1[(m * 16 + lrow) * HS + kk * 32 + lkb];
        #pragma unroll
        for (int nn = 0; nn < 2; ++nn) {
          bf16x8 b = *(const bf16x8*)&W2p[((kk * 16 + nt0 + nn) * 64 + lane) * 8];
          #pragma unroll
          for (int m = 0; m < 4; ++m)
            acc[m][nn] = __builtin_amdgcn_mfma_f32_16x16x32_bf16(a[m], b, acc[m][nn], 0, 0, 0);
        }
      }
      #pragma unroll
      for (int nn = 0; nn < 2; ++nn) {
        float bias = b2[(nt0 + nn) * 16 + lrow];
        #pragma unroll
        for (int m = 0; m < 4; ++m) {
          #pragma unroll
          for (int i = 0; i < 4; ++i) {
            float v = acc[m][nn][i] + bias;
            v = v > 0.f ? v : 0.f;
            H2[(m * 16 + crow + i) * HS + (nt0 + nn) * 16 + lrow] = f32_to_bf16(v);
          }
        }
      }
    }
    __syncthreads();

    // ---- layer 3: H2[64x256] @ W3p -> y[64x96]; cols 0..63 -> out, 64..95 -> carry
    {
      f32x4 acc[3];
      acc[0] = zero4; acc[1] = zero4; acc[2] = zero4;
      const int m = wave >> 1;           // 2 waves per m-tile
      const int ntb = (wave & 1) * 3;    // n-tiles {0,1,2} or {3,4,5}
      #pragma unroll
      for (int kk = 0; kk < 8; ++kk) {
        bf16x8 a = *(const bf16x8*)&H2[(m * 16 + lrow) * HS + kk * 32 + lkb];
        #pragma unroll
        for (int j = 0; j < 3; ++j) {
          bf16x8 b = *(const bf16x8*)&W3p[((kk * 6 + ntb + j) * 64 + lane) * 8];
          acc[j] = __builtin_amdgcn_mfma_f32_16x16x32_bf16(a, b, acc[j], 0, 0, 0);
        }
      }
      #pragma unroll
      for (int j = 0; j < 3; ++j) {
        int nt = ntb + j;
        float bias = b3[nt * 16 + lrow];
        #pragma unroll
        for (int i = 0; i < 4; ++i) {
          float v = acc[j][i] + bias;
          int r = m * 16 + crow + i;
          if (nt < 4) {
            out[(size_t)(row0 + r) * 1024 + p * 64 + nt * 16 + lrow] = v;
          } else {
            X[r * XS + 130 + (nt - 4) * 16 + lrow] = f32_to_bf16(v);
          }
        }
      }
    }
    // next iteration's build-sync orders carry writes before GEMM1 reads
  }
}

extern "C" void kernel_launch(void* const* d_in, const int* in_sizes, int n_in,
                              void* d_out, int out_size, void* d_ws, size_t ws_size,
                              hipStream_t stream) {
  const float* bias_a = (const float*)d_in[0];
  const float* bias_b = (const float*)d_in[1];
  const float* op     = (const float*)d_in[2];
  const float* W1     = (const float*)d_in[3];
  const float* b1     = (const float*)d_in[4];
  const float* W2     = (const float*)d_in[5];
  const float* b2     = (const float*)d_in[6];
  const float* W3     = (const float*)d_in[7];
  const float* b3     = (const float*)d_in[8];
  float* out = (float*)d_out;
  unsigned short* wp = (unsigned short*)d_ws;

  const int lds_bytes = (64 * XS + 2 * 64 * HS) * 2;  // 93184
  hipFuncSetAttribute((const void*)scan_kernel,
                      hipFuncAttributeMaxDynamicSharedMemorySize, lds_bytes);

  pack_weights_kernel<<<544, 256, 0, stream>>>(W1, W2, W3, wp);
  scan_kernel<<<256, 512, lds_bytes, stream>>>(bias_a, bias_b, op, b1, b2, b3, wp, out);
}

// Round 2
// 134.112 us; speedup vs baseline: 1.3410x; 1.3410x over previous
//
#include <hip/hip_runtime.h>

// SlotEquivariantHead: 16-step digit scan; per step a 3-layer MLP (162->256->256->96),
// 32 carry dims fed back. B=16384 rows.
// Round 2: 4 waves/block (256 thr), 64 rows/block, grid 256 (1 block/CU).
// W1/W2 MFMA B-fragments pinned in registers (per-wave nt-quad), W3 in LDS.
// All LDS activation tiles XOR-swizzled (16B-chunk ^ row) -> conflict-free ds_read_b128.
// a/b digits prefetched to VGPRs one position ahead, converted f32->bf16 via v_cvt_pk.

typedef __attribute__((ext_vector_type(8))) short bf16x8;
typedef __attribute__((ext_vector_type(4))) float f32x4;
typedef __attribute__((ext_vector_type(4))) unsigned int u32x4;

#define LDS_XAB 0        // [64][128] bf16, 256B rows, 16 chunks, swz ^(r&15)
#define LDS_XC  16384    // [64][64]  bf16, 128B rows,  8 chunks, swz ^(r&7)
#define LDS_H1  24576    // [64][256] bf16, 512B rows, 32 chunks, swz ^(r&15)
#define LDS_H2  57344
#define LDS_W3  90112    // 48KB packed W3 fragments (frag-linear)
#define LDS_TOTAL 139264

__device__ inline unsigned short f32_to_bf16(float f) {
  unsigned int u = __builtin_bit_cast(unsigned int, f);
  u += 0x7FFFu + ((u >> 16) & 1u);
  return (unsigned short)(u >> 16);
}

__device__ inline unsigned int cvt_pk_bf16(float lo, float hi) {
  unsigned int r;
  asm("v_cvt_pk_bf16_f32 %0, %1, %2" : "=v"(r) : "v"(lo), "v"(hi));
  return r;
}

// Pack W1 (162x256, K-pad to 192), W2 (256x256), W3 (256x96) into bf16 MFMA
// B-fragment layout: frag(kk,nt): lane l, elem j <- W[kk*32 + (l>>4)*8 + j][nt*16 + (l&15)]
// d_ws elems: W1p [0,49152), W2p [49152,114688), W3p [114688,139264)
__global__ void pack_weights_kernel(const float* __restrict__ W1,
                                    const float* __restrict__ W2,
                                    const float* __restrict__ W3,
                                    unsigned short* __restrict__ wp) {
  int idx = blockIdx.x * 256 + threadIdx.x;
  if (idx >= 139264) return;
  const float* W; int K, N, NT, e;
  if (idx < 49152)       { W = W1; K = 162; N = 256; NT = 16; e = idx; }
  else if (idx < 114688) { W = W2; K = 256; N = 256; NT = 16; e = idx - 49152; }
  else                   { W = W3; K = 256; N = 96;  NT = 6;  e = idx - 114688; }
  int j = e & 7, lane = (e >> 3) & 63, frag = e >> 9;
  int nt = frag % NT, kk = frag / NT;
  int k = kk * 32 + ((lane >> 4) << 3) + j;
  int n = nt * 16 + (lane & 15);
  float v = (k < K) ? W[k * N + n] : 0.0f;
  wp[idx] = f32_to_bf16(v);
}

__global__ __launch_bounds__(256, 1) void scan_kernel(
    const float* __restrict__ Ain, const float* __restrict__ Bin,
    const float* __restrict__ Op,
    const float* __restrict__ b1, const float* __restrict__ b2,
    const float* __restrict__ b3,
    const unsigned short* __restrict__ wp,
    float* __restrict__ out) {
  extern __shared__ char lds[];
  char* XAB = lds + LDS_XAB;
  char* XC  = lds + LDS_XC;
  char* H1  = lds + LDS_H1;
  char* H2  = lds + LDS_H2;
  char* W3L = lds + LDS_W3;

  const int tid  = threadIdx.x;
  const int wave = tid >> 6, lane = tid & 63;
  const int lrow = lane & 15, q = lane >> 4;
  const int mg = wave >> 1, ng = wave & 1;
  const int row0 = blockIdx.x * 64;

  // ---- persistent weight fragments (nt = wave*4 + n)
  bf16x8 w1[24], w2[32];
  {
    const char* wb = (const char*)wp;
    #pragma unroll
    for (int kk = 0; kk < 6; ++kk)
      #pragma unroll
      for (int n = 0; n < 4; ++n)
        w1[kk*4+n] = *(const bf16x8*)(wb + (size_t)(kk*16 + wave*4 + n)*1024 + lane*16);
    const char* wb2 = wb + 98304;
    #pragma unroll
    for (int kk = 0; kk < 8; ++kk)
      #pragma unroll
      for (int n = 0; n < 4; ++n)
        w2[kk*4+n] = *(const bf16x8*)(wb2 + (size_t)(kk*16 + wave*4 + n)*1024 + lane*16);
  }
  float b1v[4], b2v[4], b3v[3];
  #pragma unroll
  for (int n = 0; n < 4; ++n) {
    b1v[n] = b1[(wave*4+n)*16 + lrow];
    b2v[n] = b2[(wave*4+n)*16 + lrow];
  }
  #pragma unroll
  for (int j = 0; j < 3; ++j) b3v[j] = b3[(ng*3+j)*16 + lrow];

  // ---- W3 fragments -> LDS (one-time, frag-linear => lane-linear reads)
  {
    const char* w3src = (const char*)wp + 229376;
    for (int i = tid; i < 3072; i += 256)
      *(u32x4*)(W3L + (size_t)i*16) = *(const u32x4*)(w3src + (size_t)i*16);
  }
  // ---- Xc init: op cols 0,1; carry cols 2..33 = 0; pad = 0
  for (int i = tid; i < 4096; i += 256) {
    int r = i >> 6, c = i & 63;
    unsigned short v = 0;
    if (c < 2) v = f32_to_bf16(Op[(size_t)(row0 + r)*2 + c]);
    *(unsigned short*)(XC + r*128 + ((c*2) ^ ((r & 7) << 4))) = v;
  }

  // ---- a/b staging: thread covers Xab row srow, cols part*32..+31
  const int part = tid & 3;
  const int srow = tid >> 2;
  const float* srcp = (part < 2 ? Ain : Bin) + (size_t)(row0 + srow)*1024 + (part & 1)*32;
  float4 pf[8];

  // p=0 synchronous stage
  #pragma unroll
  for (int j = 0; j < 8; ++j) pf[j] = *(const float4*)(srcp + j*4);
  #pragma unroll
  for (int jj = 0; jj < 4; ++jj) {
    u32x4 t;
    t.x = cvt_pk_bf16(pf[2*jj].x,   pf[2*jj].y);
    t.y = cvt_pk_bf16(pf[2*jj].z,   pf[2*jj].w);
    t.z = cvt_pk_bf16(pf[2*jj+1].x, pf[2*jj+1].y);
    t.w = cvt_pk_bf16(pf[2*jj+1].z, pf[2*jj+1].w);
    int c = part*4 + jj;
    *(u32x4*)(XAB + srow*256 + ((c ^ (srow & 15)) * 16)) = t;
  }
  // prefetch p=1
  #pragma unroll
  for (int j = 0; j < 8; ++j) pf[j] = *(const float4*)(srcp + 64 + j*4);
  __syncthreads();

  const f32x4 zero4 = {0.f, 0.f, 0.f, 0.f};

  #pragma unroll 1
  for (int p = 0; p < 16; ++p) {
    // ================= phase 1: X[64x192] @ W1 -> relu -> H1 =================
    {
      f32x4 acc[4][4];  // [n][m]
      #pragma unroll
      for (int n = 0; n < 4; ++n)
        #pragma unroll
        for (int m = 0; m < 4; ++m) acc[n][m] = zero4;
      #pragma unroll
      for (int m = 0; m < 4; ++m) {
        const int r = m*16 + lrow;
        bf16x8 a[6];
        #pragma unroll
        for (int kk = 0; kk < 4; ++kk)
          a[kk] = *(const bf16x8*)(XAB + r*256 + ((kk*64 + q*16) ^ (lrow << 4)));
        #pragma unroll
        for (int kk = 0; kk < 2; ++kk)
          a[4+kk] = *(const bf16x8*)(XC + r*128 + ((kk*64 + q*16) ^ ((lrow & 7) << 4)));
        #pragma unroll
        for (int kk = 0; kk < 6; ++kk)
          #pragma unroll
          for (int n = 0; n < 4; ++n)
            acc[n][m] = __builtin_amdgcn_mfma_f32_16x16x32_bf16(a[kk], w1[kk*4+n], acc[n][m], 0, 0, 0);
      }
      #pragma unroll
      for (int n = 0; n < 4; ++n) {
        const int cb = (wave*4+n)*32 + lrow*2;
        #pragma unroll
        for (int m = 0; m < 4; ++m) {
          const int r = m*16 + q*4;
          float v0 = fmaxf(acc[n][m][0] + b1v[n], 0.f);
          float v1 = fmaxf(acc[n][m][1] + b1v[n], 0.f);
          float v2 = fmaxf(acc[n][m][2] + b1v[n], 0.f);
          float v3 = fmaxf(acc[n][m][3] + b1v[n], 0.f);
          unsigned int u01 = cvt_pk_bf16(v0, v1);
          unsigned int u23 = cvt_pk_bf16(v2, v3);
          *(unsigned short*)(H1 + (r+0)*512 + (cb ^ (((r+0) & 15) << 4))) = (unsigned short)u01;
          *(unsigned short*)(H1 + (r+1)*512 + (cb ^ (((r+1) & 15) << 4))) = (unsigned short)(u01 >> 16);
          *(unsigned short*)(H1 + (r+2)*512 + (cb ^ (((r+2) & 15) << 4))) = (unsigned short)u23;
          *(unsigned short*)(H1 + (r+3)*512 + (cb ^ (((r+3) & 15) << 4))) = (unsigned short)(u23 >> 16);
        }
      }
    }
    __syncthreads();  // B1

    // ---- stage Xab(p+1) from pf; issue prefetch for p+2 ----
    if (p < 15) {
      #pragma unroll
      for (int jj = 0; jj < 4; ++jj) {
        u32x4 t;
        t.x = cvt_pk_bf16(pf[2*jj].x,   pf[2*jj].y);
        t.y = cvt_pk_bf16(pf[2*jj].z,   pf[2*jj].w);
        t.z = cvt_pk_bf16(pf[2*jj+1].x, pf[2*jj+1].y);
        t.w = cvt_pk_bf16(pf[2*jj+1].z, pf[2*jj+1].w);
        int c = part*4 + jj;
        *(u32x4*)(XAB + srow*256 + ((c ^ (srow & 15)) * 16)) = t;
      }
      if (p < 14) {
        const float* s2 = srcp + (p+2)*64;
        #pragma unroll
        for (int j = 0; j < 8; ++j) pf[j] = *(const float4*)(s2 + j*4);
      }
    }

    // ================= phase 2: H1 @ W2 -> relu -> H2 =================
    {
      f32x4 acc[4][4];
      #pragma unroll
      for (int n = 0; n < 4; ++n)
        #pragma unroll
        for (int m = 0; m < 4; ++m) acc[n][m] = zero4;
      #pragma unroll
      for (int m = 0; m < 4; ++m) {
        const int r = m*16 + lrow;
        bf16x8 a[8];
        #pragma unroll
        for (int kk = 0; kk < 8; ++kk)
          a[kk] = *(const bf16x8*)(H1 + r*512 + ((kk*64 + q*16) ^ (lrow << 4)));
        #pragma unroll
        for (int kk = 0; kk < 8; ++kk)
          #pragma unroll
          for (int n = 0; n < 4; ++n)
            acc[n][m] = __builtin_amdgcn_mfma_f32_16x16x32_bf16(a[kk], w2[kk*4+n], acc[n][m], 0, 0, 0);
      }
      #pragma unroll
      for (int n = 0; n < 4; ++n) {
        const int cb = (wave*4+n)*32 + lrow*2;
        #pragma unroll
        for (int m = 0; m < 4; ++m) {
          const int r = m*16 + q*4;
          float v0 = fmaxf(acc[n][m][0] + b2v[n], 0.f);
          float v1 = fmaxf(acc[n][m][1] + b2v[n], 0.f);
          float v2 = fmaxf(acc[n][m][2] + b2v[n], 0.f);
          float v3 = fmaxf(acc[n][m][3] + b2v[n], 0.f);
          unsigned int u01 = cvt_pk_bf16(v0, v1);
          unsigned int u23 = cvt_pk_bf16(v2, v3);
          *(unsigned short*)(H2 + (r+0)*512 + (cb ^ (((r+0) & 15) << 4))) = (unsigned short)u01;
          *(unsigned short*)(H2 + (r+1)*512 + (cb ^ (((r+1) & 15) << 4))) = (unsigned short)(u01 >> 16);
          *(unsigned short*)(H2 + (r+2)*512 + (cb ^ (((r+2) & 15) << 4))) = (unsigned short)u23;
          *(unsigned short*)(H2 + (r+3)*512 + (cb ^ (((r+3) & 15) << 4))) = (unsigned short)(u23 >> 16);
        }
      }
    }
    __syncthreads();  // B2

    // ================= phase 3: H2 @ W3 -> y; cols<64 -> out, 64..95 -> carry =================
    {
      f32x4 acc[2][3];
      #pragma unroll
      for (int mi = 0; mi < 2; ++mi)
        #pragma unroll
        for (int j = 0; j < 3; ++j) acc[mi][j] = zero4;
      #pragma unroll
      for (int mi = 0; mi < 2; ++mi) {
        const int r = mg*32 + mi*16 + lrow;
        #pragma unroll
        for (int kk = 0; kk < 8; ++kk) {
          bf16x8 a = *(const bf16x8*)(H2 + r*512 + ((kk*64 + q*16) ^ (lrow << 4)));
          #pragma unroll
          for (int j = 0; j < 3; ++j) {
            bf16x8 b = *(const bf16x8*)(W3L + (size_t)(kk*6 + ng*3 + j)*1024 + lane*16);
            acc[mi][j] = __builtin_amdgcn_mfma_f32_16x16x32_bf16(a, b, acc[mi][j], 0, 0, 0);
          }
        }
      }
      #pragma unroll
      for (int j = 0; j < 3; ++j) {
        const int nt = ng*3 + j;
        #pragma unroll
        for (int mi = 0; mi < 2; ++mi) {
          #pragma unroll
          for (int i = 0; i < 4; ++i) {
            float v = acc[mi][j][i] + b3v[j];
            int r = mg*32 + mi*16 + q*4 + i;
            if (nt < 4) {
              out[(size_t)(row0 + r)*1024 + p*64 + nt*16 + lrow] = v;
            } else {
              int cbyte = (2 + (nt-4)*16 + lrow) * 2;
              *(unsigned short*)(XC + r*128 + (cbyte ^ ((r & 7) << 4))) = f32_to_bf16(v);
            }
          }
        }
      }
    }
    __syncthreads();  // B3
  }
}

extern "C" void kernel_launch(void* const* d_in, const int* in_sizes, int n_in,
                              void* d_out, int out_size, void* d_ws, size_t ws_size,
                              hipStream_t stream) {
  const float* bias_a = (const float*)d_in[0];
  const float* bias_b = (const float*)d_in[1];
  const float* op     = (const float*)d_in[2];
  const float* W1     = (const float*)d_in[3];
  const float* b1     = (const float*)d_in[4];
  const float* W2     = (const float*)d_in[5];
  const float* b2     = (const float*)d_in[6];
  const float* W3     = (const float*)d_in[7];
  const float* b3     = (const float*)d_in[8];
  float* out = (float*)d_out;
  unsigned short* wp = (unsigned short*)d_ws;

  hipFuncSetAttribute((const void*)scan_kernel,
                      hipFuncAttributeMaxDynamicSharedMemorySize, LDS_TOTAL);

  pack_weights_kernel<<<544, 256, 0, stream>>>(W1, W2, W3, wp);
  scan_kernel<<<256, 256, LDS_TOTAL, stream>>>(bias_a, bias_b, op, b1, b2, b3, wp, out);
}

// Round 4
// 80.288 us; speedup vs baseline: 2.2399x; 1.6704x over previous
//
#include <hip/hip_runtime.h>

// SlotEquivariantHead: 16-step digit scan; per step MLP 162->256->256->96, 32 carry fed back.
// Round 4: swapped-operand MFMA (Y^T = W^T @ X^T) so the C-fragment is 4 consecutive
// CHANNELS at fixed batch-row -> epilogue = one ds_write_b64 per tile into row-major H,
// and float4 global stores. All activation reads are the R1-verified row-major 16B
// fragment reads. 8 waves/block (512 thr), 64 rows/block, grid 256, 2 waves/SIMD.
// W1/W2 frags in VGPRs (n-split-2/wave), W3 frags in LDS. Bias folded into acc init.
// X layout: XAB [64r][128k] (a|b); XC [64r][64k] tail = [carry(32)|op(2)|zero-pad(30)]
// (W1 rows permuted at pack time to match).

typedef __attribute__((ext_vector_type(8))) short bf16x8;
typedef __attribute__((ext_vector_type(4))) float f32x4;
typedef __attribute__((ext_vector_type(2))) unsigned int u32x2;
typedef __attribute__((ext_vector_type(4))) unsigned int u32x4;

#define LDS_XAB 0        // 16 KB: [64 r][128 k] bf16, 256B rows, 16 chunks, swz chunk^(r&15)
#define LDS_XC  16384    //  8 KB: [64 r][64 k]  bf16, 128B rows,  8 chunks, swz chunk^(r&7)
#define LDS_H1  24576    // 32 KB: [64 r][256 n] bf16, 512B rows, 32 chunks, swz chunk^(r&15)
#define LDS_H2  57344    // 32 KB
#define LDS_W3  90112    // 48 KB packed W3 fragments (frag-linear)
#define LDS_TOTAL 139264

__device__ inline unsigned short f32_to_bf16(float f) {
  unsigned int u = __builtin_bit_cast(unsigned int, f);
  u += 0x7FFFu + ((u >> 16) & 1u);
  return (unsigned short)(u >> 16);
}

__device__ inline unsigned int cvt_pk_bf16(float lo, float hi) {
  unsigned int r;
  asm("v_cvt_pk_bf16_f32 %0, %1, %2" : "=v"(r) : "v"(lo), "v"(hi));
  return r;
}

// Pack W1 (rows permuted, K-pad 192), W2 (256x256), W3 (256x96) into bf16 MFMA fragment
// layout: frag(kk,nt): lane l, elem j <- W[kk*32 + (l>>4)*8 + j][nt*16 + (l&15)].
// W1 row permutation k' -> source row: [0,128) a|b direct; [128,160) carry = 130+(k'-128);
// {160,161} op = 128+(k'-160); [162,192) zero.  (matches XC tail = [carry|op|pad])
__global__ void pack_weights_kernel(const float* __restrict__ W1,
                                    const float* __restrict__ W2,
                                    const float* __restrict__ W3,
                                    unsigned short* __restrict__ wp) {
  int idx = blockIdx.x * 256 + threadIdx.x;
  if (idx >= 139264) return;
  int j, lane, frag, nt, kk, k, n;
  float v = 0.0f;
  if (idx < 49152) {
    int e = idx;
    j = e & 7; lane = (e >> 3) & 63; frag = e >> 9;
    nt = frag % 16; kk = frag / 16;
    k = kk * 32 + ((lane >> 4) << 3) + j;
    n = nt * 16 + (lane & 15);
    int ksrc;
    if (k < 128)      ksrc = k;
    else if (k < 160) ksrc = 130 + (k - 128);   // carry rows
    else if (k < 162) ksrc = 128 + (k - 160);   // op rows
    else              ksrc = -1;                 // zero pad
    v = (ksrc >= 0) ? W1[ksrc * 256 + n] : 0.0f;
  } else if (idx < 114688) {
    int e = idx - 49152;
    j = e & 7; lane = (e >> 3) & 63; frag = e >> 9;
    nt = frag % 16; kk = frag / 16;
    k = kk * 32 + ((lane >> 4) << 3) + j;
    n = nt * 16 + (lane & 15);
    v = W2[k * 256 + n];
  } else {
    int e = idx - 114688;
    j = e & 7; lane = (e >> 3) & 63; frag = e >> 9;
    nt = frag % 6; kk = frag / 6;
    k = kk * 32 + ((lane >> 4) << 3) + j;
    n = nt * 16 + (lane & 15);
    v = W3[k * 96 + n];
  }
  wp[idx] = f32_to_bf16(v);
}

__global__ __launch_bounds__(512, 2) void scan_kernel(
    const float* __restrict__ Ain, const float* __restrict__ Bin,
    const float* __restrict__ Op,
    const float* __restrict__ b1, const float* __restrict__ b2,
    const float* __restrict__ b3,
    const unsigned short* __restrict__ wp,
    float* __restrict__ out) {
  extern __shared__ char lds[];

  const int tid  = threadIdx.x;
  const int wave = tid >> 6, lane = tid & 63;
  const int lcol = lane & 15;      // batch-row within tile (D "col")
  const int q    = lane >> 4;      // k-quad for reads; n-quad for writes
  const int row0 = blockIdx.x * 64;
  const int mw = wave >> 1, ngg = wave & 1;

  // ---- persistent weight fragments: wave owns nt = wave*2 + n (n = 0,1)
  bf16x8 w1f[12], w2f[16];
  {
    const char* wb = (const char*)wp;
    #pragma unroll
    for (int kk = 0; kk < 6; ++kk)
      #pragma unroll
      for (int n = 0; n < 2; ++n)
        w1f[kk*2+n] = *(const bf16x8*)(wb + (size_t)(kk*16 + wave*2 + n)*1024 + lane*16);
    const char* wb2 = wb + 98304;
    #pragma unroll
    for (int kk = 0; kk < 8; ++kk)
      #pragma unroll
      for (int n = 0; n < 2; ++n)
        w2f[kk*2+n] = *(const bf16x8*)(wb2 + (size_t)(kk*16 + wave*2 + n)*1024 + lane*16);
  }
  // ---- bias vectors for accumulator init (4 consecutive channels per lane)
  f32x4 b1i[2], b2i[2], b3i[3];
  #pragma unroll
  for (int n = 0; n < 2; ++n)
    #pragma unroll
    for (int i = 0; i < 4; ++i) {
      b1i[n][i] = b1[(wave*2+n)*16 + q*4 + i];
      b2i[n][i] = b2[(wave*2+n)*16 + q*4 + i];
    }
  #pragma unroll
  for (int j = 0; j < 3; ++j)
    #pragma unroll
    for (int i = 0; i < 4; ++i)
      b3i[j][i] = b3[(ngg*3+j)*16 + q*4 + i];

  // ---- W3 fragments -> LDS (one-time, frag-linear => lane-linear conflict-free reads)
  {
    const char* w3src = (const char*)wp + 229376;
    #pragma unroll
    for (int i = 0; i < 6; ++i)
      *(u32x4*)(lds + LDS_W3 + (size_t)(tid + i*512)*16) =
          *(const u32x4*)(w3src + (size_t)(tid + i*512)*16);
  }
  // ---- XC init: k 0..31 carry=0, 32..33 op, 34..63 zero
  for (int i = tid; i < 4096; i += 512) {
    int r = i >> 6, kx = i & 63;
    unsigned short v = 0;
    if (kx == 32 || kx == 33) v = f32_to_bf16(Op[(size_t)(row0 + r)*2 + (kx - 32)]);
    int chunk = kx >> 3, within = (kx & 7) * 2;
    *(unsigned short*)(lds + LDS_XC + r*128 + ((chunk ^ (r & 7)) << 4) + within) = v;
  }

  // ---- a/b staging: thread covers row srow, 16 floats at part*16 of the 128-col [a|b] row
  const int part = tid & 7;
  const int srow = tid >> 3;
  const float* srcp = (part < 4 ? Ain : Bin) + (size_t)(row0 + srow)*1024 + (part & 3)*16;
  float4 pf[4];

  {  // p=0 synchronous stage + p=1 prefetch
    #pragma unroll
    for (int jj = 0; jj < 4; ++jj) pf[jj] = *(const float4*)(srcp + jj*4);
    unsigned int u[8];
    #pragma unroll
    for (int jj = 0; jj < 4; ++jj) {
      u[jj*2]   = cvt_pk_bf16(pf[jj].x, pf[jj].y);
      u[jj*2+1] = cvt_pk_bf16(pf[jj].z, pf[jj].w);
    }
    u32x4 t0 = {u[0],u[1],u[2],u[3]}, t1 = {u[4],u[5],u[6],u[7]};
    *(u32x4*)(lds + LDS_XAB + srow*256 + (((part*2)   ^ (srow & 15)) << 4)) = t0;
    *(u32x4*)(lds + LDS_XAB + srow*256 + (((part*2+1) ^ (srow & 15)) << 4)) = t1;
    #pragma unroll
    for (int jj = 0; jj < 4; ++jj) pf[jj] = *(const float4*)(srcp + 64 + jj*4);
  }
  __syncthreads();

  #pragma unroll 1
  for (int p = 0; p < 16; ++p) {
    // ============ phase 1: Y^T = W1^T @ X^T -> relu -> H1 [64r][256n] ============
    {
      f32x4 acc[2][4];   // [n][m-rtile]
      #pragma unroll
      for (int n = 0; n < 2; ++n)
        #pragma unroll
        for (int m = 0; m < 4; ++m) acc[n][m] = b1i[n];
      #pragma unroll
      for (int m = 0; m < 4; ++m) {
        const int r = m*16 + lcol;
        bf16x8 xf[6];
        #pragma unroll
        for (int kk = 0; kk < 4; ++kk)
          xf[kk] = *(const bf16x8*)(lds + LDS_XAB + r*256 + (((4*kk + q) ^ lcol) << 4));
        #pragma unroll
        for (int kk = 0; kk < 2; ++kk)
          xf[4+kk] = *(const bf16x8*)(lds + LDS_XC + r*128 + (((4*kk + q) ^ (lcol & 7)) << 4));
        __builtin_amdgcn_s_setprio(1);
        #pragma unroll
        for (int kk = 0; kk < 6; ++kk) {
          acc[0][m] = __builtin_amdgcn_mfma_f32_16x16x32_bf16(w1f[kk*2+0], xf[kk], acc[0][m], 0,0,0);
          acc[1][m] = __builtin_amdgcn_mfma_f32_16x16x32_bf16(w1f[kk*2+1], xf[kk], acc[1][m], 0,0,0);
        }
        __builtin_amdgcn_s_setprio(0);
      }
      #pragma unroll
      for (int n = 0; n < 2; ++n) {
        const int nbyte = (wave*2+n)*32 + q*8;          // (nt*16 + q*4) channels * 2B
        const int chunk = nbyte >> 4, within = nbyte & 15;
        #pragma unroll
        for (int m = 0; m < 4; ++m) {
          const int r = m*16 + lcol;
          float v0 = fmaxf(acc[n][m][0], 0.f);
          float v1 = fmaxf(acc[n][m][1], 0.f);
          float v2 = fmaxf(acc[n][m][2], 0.f);
          float v3 = fmaxf(acc[n][m][3], 0.f);
          u32x2 t; t.x = cvt_pk_bf16(v0, v1); t.y = cvt_pk_bf16(v2, v3);
          *(u32x2*)(lds + LDS_H1 + r*512 + ((chunk ^ lcol) << 4) + within) = t;
        }
      }
    }
    __syncthreads();  // B1

    // ---- stage XAB(p+1) from pf; prefetch p+2 ----
    if (p < 15) {
      unsigned int u[8];
      #pragma unroll
      for (int jj = 0; jj < 4; ++jj) {
        u[jj*2]   = cvt_pk_bf16(pf[jj].x, pf[jj].y);
        u[jj*2+1] = cvt_pk_bf16(pf[jj].z, pf[jj].w);
      }
      u32x4 t0 = {u[0],u[1],u[2],u[3]}, t1 = {u[4],u[5],u[6],u[7]};
      *(u32x4*)(lds + LDS_XAB + srow*256 + (((part*2)   ^ (srow & 15)) << 4)) = t0;
      *(u32x4*)(lds + LDS_XAB + srow*256 + (((part*2+1) ^ (srow & 15)) << 4)) = t1;
      if (p < 14) {
        const float* s2 = srcp + (p+2)*64;
        #pragma unroll
        for (int jj = 0; jj < 4; ++jj) pf[jj] = *(const float4*)(s2 + jj*4);
      }
    }

    // ============ phase 2: W2^T @ H1^T -> relu -> H2 ============
    {
      f32x4 acc[2][4];
      #pragma unroll
      for (int n = 0; n < 2; ++n)
        #pragma unroll
        for (int m = 0; m < 4; ++m) acc[n][m] = b2i[n];
      #pragma unroll
      for (int m = 0; m < 4; ++m) {
        const int r = m*16 + lcol;
        bf16x8 hf[8];
        #pragma unroll
        for (int kk = 0; kk < 8; ++kk)
          hf[kk] = *(const bf16x8*)(lds + LDS_H1 + r*512 + (((4*kk + q) ^ lcol) << 4));
        __builtin_amdgcn_s_setprio(1);
        #pragma unroll
        for (int kk = 0; kk < 8; ++kk) {
          acc[0][m] = __builtin_amdgcn_mfma_f32_16x16x32_bf16(w2f[kk*2+0], hf[kk], acc[0][m], 0,0,0);
          acc[1][m] = __builtin_amdgcn_mfma_f32_16x16x32_bf16(w2f[kk*2+1], hf[kk], acc[1][m], 0,0,0);
        }
        __builtin_amdgcn_s_setprio(0);
      }
      #pragma unroll
      for (int n = 0; n < 2; ++n) {
        const int nbyte = (wave*2+n)*32 + q*8;
        const int chunk = nbyte >> 4, within = nbyte & 15;
        #pragma unroll
        for (int m = 0; m < 4; ++m) {
          const int r = m*16 + lcol;
          float v0 = fmaxf(acc[n][m][0], 0.f);
          float v1 = fmaxf(acc[n][m][1], 0.f);
          float v2 = fmaxf(acc[n][m][2], 0.f);
          float v3 = fmaxf(acc[n][m][3], 0.f);
          u32x2 t; t.x = cvt_pk_bf16(v0, v1); t.y = cvt_pk_bf16(v2, v3);
          *(u32x2*)(lds + LDS_H2 + r*512 + ((chunk ^ lcol) << 4) + within) = t;
        }
      }
    }
    __syncthreads();  // B2

    // ============ phase 3: W3^T @ H2^T -> y; nt<4 -> out (float4), nt 4,5 -> carry ============
    {
      f32x4 acc3[3] = {b3i[0], b3i[1], b3i[2]};
      const int r = mw*16 + lcol;
      #pragma unroll
      for (int kk = 0; kk < 8; ++kk) {
        bf16x8 hf = *(const bf16x8*)(lds + LDS_H2 + r*512 + (((4*kk + q) ^ lcol) << 4));
        #pragma unroll
        for (int j = 0; j < 3; ++j) {
          bf16x8 wf = *(const bf16x8*)(lds + LDS_W3 + (size_t)(kk*6 + ngg*3 + j)*1024 + lane*16);
          acc3[j] = __builtin_amdgcn_mfma_f32_16x16x32_bf16(wf, hf, acc3[j], 0,0,0);
        }
      }
      #pragma unroll
      for (int j = 0; j < 3; ++j) {
        const int nt = ngg*3 + j;
        if (nt < 4) {
          float4 o;
          o.x = acc3[j][0]; o.y = acc3[j][1]; o.z = acc3[j][2]; o.w = acc3[j][3];
          *(float4*)&out[(size_t)(row0 + r)*1024 + p*64 + nt*16 + q*4] = o;
        } else {
          const int kbyte = (nt-4)*32 + q*8;            // carry channels at XC k 0..31
          const int chunk = kbyte >> 4, within = kbyte & 15;
          u32x2 t;
          t.x = cvt_pk_bf16(acc3[j][0], acc3[j][1]);
          t.y = cvt_pk_bf16(acc3[j][2], acc3[j][3]);
          *(u32x2*)(lds + LDS_XC + r*128 + ((chunk ^ (r & 7)) << 4) + within) = t;
        }
      }
    }
    __syncthreads();  // B3
  }
}

extern "C" void kernel_launch(void* const* d_in, const int* in_sizes, int n_in,
                              void* d_out, int out_size, void* d_ws, size_t ws_size,
                              hipStream_t stream) {
  const float* bias_a = (const float*)d_in[0];
  const float* bias_b = (const float*)d_in[1];
  const float* op     = (const float*)d_in[2];
  const float* W1     = (const float*)d_in[3];
  const float* b1     = (const float*)d_in[4];
  const float* W2     = (const float*)d_in[5];
  const float* b2     = (const float*)d_in[6];
  const float* W3     = (const float*)d_in[7];
  const float* b3     = (const float*)d_in[8];
  float* out = (float*)d_out;
  unsigned short* wp = (unsigned short*)d_ws;

  hipFuncSetAttribute((const void*)scan_kernel,
                      hipFuncAttributeMaxDynamicSharedMemorySize, LDS_TOTAL);

  pack_weights_kernel<<<544, 256, 0, stream>>>(W1, W2, W3, wp);
  scan_kernel<<<256, 512, LDS_TOTAL, stream>>>(bias_a, bias_b, op, b1, b2, b3, wp, out);
}